// Round 1
// baseline (169.578 us; speedup 1.0000x reference)
//
#include <hip/hip_runtime.h>

#define HH 128
#define WW 128
#define BB 64
#define OO 32
#define LP 129   // padded LDS row pitch: 129 mod 32 = 1 -> row-steps rotate banks

// Single fused kernel. Block = (b, group of 4 o's): 512 blocks x 1024 threads
// -> exactly 2 resident blocks/CU (2 x 64.6 KiB LDS = 129.2 <= 160 KiB), 32
// waves/CU (full occupancy; __launch_bounds__(1024,8) caps VGPR at 64).
// Threads 0..3 compute the 4 per-o affine coefficient sets (pre-folded with
// the pixel-space transform) into LDS, reusing the staging barrier.
// Coordinate clamp into [0, 126.99999] replaces the reference's index clamp
// (equivalent within ~1e-5 tap weight; keeps +1/+LP taps in-bounds) so each
// bilinear row-pair compiles to one ds_read2_b32.
// LDS pitch 129 (not 128): with pitch 128 the bank index is x0 mod 32
// regardless of row, so rotated sampling (|sin| up to 0.95) makes ~3-4 lanes
// share a bank at different addresses on every gather. Pitch 129 makes a
// row-step advance the bank by 1, spreading column-direction lane runs over
// all 32 banks. ds_read2 pairing survives: offsets (0,1) and (129,130).
__launch_bounds__(1024, 8)
__global__ void sample_kernel(const float* __restrict__ X,
                              const float* __restrict__ eps,
                              const float* __restrict__ tmin,
                              const float* __restrict__ tmax,
                              float* __restrict__ out) {
    __shared__ float img[HH * LP];   // 66048 B
    __shared__ float scoef[4][6];

    const int bid = blockIdx.x;
    const int og  = bid & 7;          // consecutive blocks share b -> L2 reuse
    const int b   = bid >> 3;
    const int tid = threadIdx.x;

    if (tid < 4) {
        const int o = og * 4 + tid;
        float th[7];
#pragma unroll
        for (int i = 0; i < 7; ++i) {
            const float mn = tmin[i], mx = tmax[i];
            th[i] = mn + (mx - mn) * eps[o * 7 + i];
        }
        const float ang = th[0], sx = th[1], sy = th[2], px = th[3],
                    py = th[4], tx = th[5], ty = th[6];
        const float c = cosf(ang), s = sinf(ang);
        const float half = 0.5f * (WW - 1);  // 63.5
        scoef[tid][0] = (c * sx - s * py) * half;   // cx0
        scoef[tid][1] = (c * px - s * sy) * half;   // cx1
        scoef[tid][2] = (tx + 1.0f) * half;         // cxt
        scoef[tid][3] = (s * sx + c * py) * half;   // cy0
        scoef[tid][4] = (s * px + c * sy) * half;   // cy1
        scoef[tid][5] = (ty + 1.0f) * half;         // cyt
    }

    // Stage image b -> LDS, coalesced float4 global loads (4 per thread),
    // scattered to the padded pitch (rows stay contiguous; ds_write2_b32 pairs).
    {
        const float4* __restrict__ src = (const float4*)(X + b * (HH * WW));
#pragma unroll
        for (int i = 0; i < 4; ++i) {
            const int g = tid + i * 1024;      // float4 index, 0..4095
            const float4 v = src[g];
            const int y = g >> 5;              // 32 float4 per 128-wide row
            const int x = (g & 31) << 2;
            float* __restrict__ d = &img[y * LP + x];
            d[0] = v.x; d[1] = v.y; d[2] = v.z; d[3] = v.w;
        }
    }
    __syncthreads();

    const int w  = tid & (WW - 1);
    const int h0 = tid >> 7;                 // 0..7; wave = 256B-contiguous row chunk
    const float step  = 2.0f / 127.0f;
    const float hstep = 8.0f * step;         // row stride of the i-loop
    const float Xg  = -1.0f + w * step;
    const float Yg0 = -1.0f + h0 * step;
    const float hi  = 126.999992f;           // nextbelow(127)

#pragma unroll
    for (int j = 0; j < 4; ++j) {
        const int o = og * 4 + j;
        const float cx0 = scoef[j][0];
        const float cx1 = scoef[j][1];
        const float cxt = scoef[j][2];
        const float cy0 = scoef[j][3];
        const float cy1 = scoef[j][4];
        const float cyt = scoef[j][5];

        float x = fmaf(cx1, Yg0, fmaf(cx0, Xg, cxt));
        float y = fmaf(cy1, Yg0, fmaf(cy0, Xg, cyt));
        const float dx = cx1 * hstep;
        const float dy = cy1 * hstep;

        float* __restrict__ outp =
            out + ((size_t)(o * BB + b) * (HH * WW)) + h0 * WW + w;

#pragma unroll
        for (int i = 0; i < 16; ++i) {
            const float xc = __builtin_amdgcn_fmed3f(x, 0.0f, hi);
            const float yc = __builtin_amdgcn_fmed3f(y, 0.0f, hi);
            const float x0f = floorf(xc);
            const float y0f = floorf(yc);
            const float wx = xc - x0f;
            const float wy = yc - y0f;
            const int idx = (int)fmaf(y0f, (float)LP, x0f);  // exact (< 2^24)

            const float Ia = img[idx];
            const float Ic = img[idx + 1];        // ds_read2_b32 with Ia (off 0,1)
            const float Ib = img[idx + LP];
            const float Id = img[idx + LP + 1];   // ds_read2_b32 with Ib (off 129,130)

            const float top = fmaf(wx, Ic - Ia, Ia);
            const float bot = fmaf(wx, Id - Ib, Ib);
            *outp = fmaf(wy, bot - top, top);

            outp += 8 * WW;
            x += dx;
            y += dy;
        }
    }
}

extern "C" void kernel_launch(void* const* d_in, const int* in_sizes, int n_in,
                              void* d_out, int out_size, void* d_ws, size_t ws_size,
                              hipStream_t stream) {
    const float* X    = (const float*)d_in[0];
    const float* eps  = (const float*)d_in[1];
    const float* tmin = (const float*)d_in[2];
    const float* tmax = (const float*)d_in[3];
    float* out = (float*)d_out;

    const int nblocks = BB * 8;  // 512: 2 per CU, LDS-capped full occupancy
    sample_kernel<<<nblocks, 1024, 0, stream>>>(X, eps, tmin, tmax, out);
}

// Round 2
// 149.959 us; speedup vs baseline: 1.1308x; 1.1308x over previous
//
#include <hip/hip_runtime.h>

#define HH 128
#define WW 128
#define BB 64
#define OO 32
#define LP 132   // padded LDS row pitch: 132 mod 32 = 4 -> row-steps rotate banks,
                 // and 132*4B = 528B keeps rows 16B-aligned -> ds_write_b128 staging

// Single fused kernel. Block = (b, group of 4 o's): 512 blocks x 1024 threads
// -> exactly 2 resident blocks/CU (2 x 66.1 KiB LDS <= 160 KiB), 32 waves/CU
// (full occupancy; __launch_bounds__(1024,8) caps VGPR at 64).
// Threads 0..3 compute the 4 per-o affine coefficient sets (pre-folded with
// the pixel-space transform) into LDS, reusing the staging barrier.
// Coordinate clamp into [0, 126.99999] replaces the reference's index clamp
// (equivalent within ~1e-5 tap weight; keeps +1/+LP taps in-bounds) so each
// bilinear row-pair compiles to one ds_read2_b32 (offsets 0,1 and 132,133).
// Pitch note: 128 makes bank = x0 mod 32 independent of row, so rotated
// sampling (|sin| up to 0.95, ~38% of o's) aliases 3-4 lanes per bank at
// DIFFERENT rows -> serialized. 129 broke the 16B staging alignment (round-1
// regression: scattered ds_write_b32 + VGPR pressure at the 64-reg cap).
// 132 gives bank rotation of 4/row AND preserves float4 staging: float4
// destination index is g + (g>>5).
__launch_bounds__(1024, 8)
__global__ void sample_kernel(const float* __restrict__ X,
                              const float* __restrict__ eps,
                              const float* __restrict__ tmin,
                              const float* __restrict__ tmax,
                              float* __restrict__ out) {
    __shared__ float img[HH * LP];   // 67584 B
    __shared__ float scoef[4][6];

    const int bid = blockIdx.x;
    const int og  = bid & 7;          // consecutive blocks share b -> L2 reuse
    const int b   = bid >> 3;
    const int tid = threadIdx.x;

    if (tid < 4) {
        const int o = og * 4 + tid;
        float th[7];
#pragma unroll
        for (int i = 0; i < 7; ++i) {
            const float mn = tmin[i], mx = tmax[i];
            th[i] = mn + (mx - mn) * eps[o * 7 + i];
        }
        const float ang = th[0], sx = th[1], sy = th[2], px = th[3],
                    py = th[4], tx = th[5], ty = th[6];
        const float c = cosf(ang), s = sinf(ang);
        const float half = 0.5f * (WW - 1);  // 63.5
        scoef[tid][0] = (c * sx - s * py) * half;   // cx0
        scoef[tid][1] = (c * px - s * sy) * half;   // cx1
        scoef[tid][2] = (tx + 1.0f) * half;         // cxt
        scoef[tid][3] = (s * sx + c * py) * half;   // cy0
        scoef[tid][4] = (s * px + c * sy) * half;   // cy1
        scoef[tid][5] = (ty + 1.0f) * half;         // cyt
    }

    // Stage image b -> LDS, coalesced float4 loads AND float4 LDS writes
    // (row pitch 132 floats = 33 float4; dest float4 index = g + g/32).
    {
        const float4* __restrict__ src = (const float4*)(X + b * (HH * WW));
        float4* __restrict__ dst = (float4*)img;
#pragma unroll
        for (int i = 0; i < 4; ++i) {
            const int g = tid + i * 1024;      // float4 index, 0..4095
            dst[g + (g >> 5)] = src[g];        // ds_write_b128, 16B-aligned
        }
    }
    __syncthreads();

    const int w  = tid & (WW - 1);
    const int h0 = tid >> 7;                 // 0..7; wave = 256B-contiguous row chunk
    const float step  = 2.0f / 127.0f;
    const float hstep = 8.0f * step;         // row stride of the i-loop
    const float Xg  = -1.0f + w * step;
    const float Yg0 = -1.0f + h0 * step;
    const float hi  = 126.999992f;           // nextbelow(127)

#pragma unroll
    for (int j = 0; j < 4; ++j) {
        const int o = og * 4 + j;
        const float cx0 = scoef[j][0];
        const float cx1 = scoef[j][1];
        const float cxt = scoef[j][2];
        const float cy0 = scoef[j][3];
        const float cy1 = scoef[j][4];
        const float cyt = scoef[j][5];

        float x = fmaf(cx1, Yg0, fmaf(cx0, Xg, cxt));
        float y = fmaf(cy1, Yg0, fmaf(cy0, Xg, cyt));
        const float dx = cx1 * hstep;
        const float dy = cy1 * hstep;

        float* __restrict__ outp =
            out + ((size_t)(o * BB + b) * (HH * WW)) + h0 * WW + w;

#pragma unroll
        for (int i = 0; i < 16; ++i) {
            const float xc = __builtin_amdgcn_fmed3f(x, 0.0f, hi);
            const float yc = __builtin_amdgcn_fmed3f(y, 0.0f, hi);
            const float x0f = floorf(xc);
            const float y0f = floorf(yc);
            const float wx = xc - x0f;
            const float wy = yc - y0f;
            const int idx = (int)fmaf(y0f, (float)LP, x0f);  // exact (< 2^24)

            const float Ia = img[idx];
            const float Ic = img[idx + 1];        // ds_read2_b32 with Ia (off 0,1)
            const float Ib = img[idx + LP];
            const float Id = img[idx + LP + 1];   // ds_read2_b32 with Ib (off 132,133)

            const float top = fmaf(wx, Ic - Ia, Ia);
            const float bot = fmaf(wx, Id - Ib, Ib);
            *outp = fmaf(wy, bot - top, top);

            outp += 8 * WW;
            x += dx;
            y += dy;
        }
    }
}

extern "C" void kernel_launch(void* const* d_in, const int* in_sizes, int n_in,
                              void* d_out, int out_size, void* d_ws, size_t ws_size,
                              hipStream_t stream) {
    const float* X    = (const float*)d_in[0];
    const float* eps  = (const float*)d_in[1];
    const float* tmin = (const float*)d_in[2];
    const float* tmax = (const float*)d_in[3];
    float* out = (float*)d_out;

    const int nblocks = BB * 8;  // 512: 2 per CU, LDS-capped full occupancy
    sample_kernel<<<nblocks, 1024, 0, stream>>>(X, eps, tmin, tmax, out);
}

// Round 3
// 149.487 us; speedup vs baseline: 1.1344x; 1.0032x over previous
//
#include <hip/hip_runtime.h>

#define HH 128
#define WW 128
#define BB 64
#define OO 32
#define LP 132   // padded LDS pitch: rows 16B-aligned (float4 staging), mild bank rotation

// Block = (b, group of 4 o's): 512 blocks x 512 threads, 2 blocks/CU
// (LDS-capped: 2 x 66.1 KiB <= 160 KiB) -> 16 waves/CU.
// ROUND-3 AXIS: __launch_bounds__(512,4) raises the VGPR cap to 128 (was 64
// at 1024x8). The 64-reg cap strangled ILP: the unrolled bilinear stream
// needs ~6 live regs per in-flight iteration (2 addrs + 4 LDS results) plus
// coefficients and 64-bit store pointers, so at 64 regs the scheduler could
// pipeline only ~2 iterations (round-1's +17us from slightly more staging
// pressure = spill-edge signature). 128 regs + a compact rolled i-loop
// (unroll 8) lets each wave cover ds_read latency with ILP; TLP drops from
// 8 to 4 waves/SIMD, which the deeper per-wave pipelining should more than
// repay if the theory is right.
// Coordinate clamp into [0, 126.99999] replaces the reference's index clamp
// (equivalent within ~1e-5 tap weight; keeps +1/+LP taps in-bounds) so each
// bilinear row-pair compiles to one ds_read2_b32 (offsets 0,1 / 132,133).
__launch_bounds__(512, 4)
__global__ void sample_kernel(const float* __restrict__ X,
                              const float* __restrict__ eps,
                              const float* __restrict__ tmin,
                              const float* __restrict__ tmax,
                              float* __restrict__ out) {
    __shared__ float img[HH * LP];   // 67584 B
    __shared__ float scoef[4][6];

    const int bid = blockIdx.x;
    const int og  = bid & 7;          // consecutive blocks share b -> L2 reuse
    const int b   = bid >> 3;
    const int tid = threadIdx.x;

    if (tid < 4) {
        const int o = og * 4 + tid;
        float th[7];
#pragma unroll
        for (int i = 0; i < 7; ++i) {
            const float mn = tmin[i], mx = tmax[i];
            th[i] = mn + (mx - mn) * eps[o * 7 + i];
        }
        const float ang = th[0], sx = th[1], sy = th[2], px = th[3],
                    py = th[4], tx = th[5], ty = th[6];
        const float c = cosf(ang), s = sinf(ang);
        const float half = 0.5f * (WW - 1);  // 63.5
        scoef[tid][0] = (c * sx - s * py) * half;   // cx0
        scoef[tid][1] = (c * px - s * sy) * half;   // cx1
        scoef[tid][2] = (tx + 1.0f) * half;         // cxt
        scoef[tid][3] = (s * sx + c * py) * half;   // cy0
        scoef[tid][4] = (s * px + c * sy) * half;   // cy1
        scoef[tid][5] = (ty + 1.0f) * half;         // cyt
    }

    // Stage image b -> LDS: coalesced float4 loads AND float4 LDS writes
    // (pitch 132 floats = 33 float4; dest float4 index = g + g/32).
    {
        const float4* __restrict__ src = (const float4*)(X + b * (HH * WW));
        float4* __restrict__ dst = (float4*)img;
#pragma unroll
        for (int i = 0; i < 8; ++i) {
            const int g = tid + i * 512;       // float4 index, 0..4095
            dst[g + (g >> 5)] = src[g];        // ds_write_b128, 16B-aligned
        }
    }
    __syncthreads();

    const int w  = tid & (WW - 1);
    const int h0 = tid >> 7;                 // 0..3; wave = 64-px row chunk
    const float step  = 2.0f / 127.0f;
    const float hstep = 4.0f * step;         // row stride of the i-loop
    const float Xg  = -1.0f + w * step;
    const float Yg0 = -1.0f + h0 * step;
    const float hi  = 126.999992f;           // nextbelow(127)

#pragma unroll
    for (int j = 0; j < 4; ++j) {
        const int o = og * 4 + j;
        const float cx0 = scoef[j][0];
        const float cx1 = scoef[j][1];
        const float cxt = scoef[j][2];
        const float cy0 = scoef[j][3];
        const float cy1 = scoef[j][4];
        const float cyt = scoef[j][5];

        float x = fmaf(cx1, Yg0, fmaf(cx0, Xg, cxt));
        float y = fmaf(cy1, Yg0, fmaf(cy0, Xg, cyt));
        const float dx = cx1 * hstep;
        const float dy = cy1 * hstep;

        float* __restrict__ outp =
            out + ((size_t)(o * BB + b) * (HH * WW)) + h0 * WW + w;

#pragma unroll 8
        for (int i = 0; i < 32; ++i) {
            const float xc = __builtin_amdgcn_fmed3f(x, 0.0f, hi);
            const float yc = __builtin_amdgcn_fmed3f(y, 0.0f, hi);
            const float x0f = floorf(xc);
            const float y0f = floorf(yc);
            const float wx = xc - x0f;
            const float wy = yc - y0f;
            const int idx = (int)fmaf(y0f, (float)LP, x0f);  // exact (< 2^24)

            const float Ia = img[idx];
            const float Ic = img[idx + 1];        // ds_read2_b32 with Ia (off 0,1)
            const float Ib = img[idx + LP];
            const float Id = img[idx + LP + 1];   // ds_read2_b32 with Ib (off 132,133)

            const float top = fmaf(wx, Ic - Ia, Ia);
            const float bot = fmaf(wx, Id - Ib, Ib);
            *outp = fmaf(wy, bot - top, top);

            outp += 4 * WW;
            x += dx;
            y += dy;
        }
    }
}

extern "C" void kernel_launch(void* const* d_in, const int* in_sizes, int n_in,
                              void* d_out, int out_size, void* d_ws, size_t ws_size,
                              hipStream_t stream) {
    const float* X    = (const float*)d_in[0];
    const float* eps  = (const float*)d_in[1];
    const float* tmin = (const float*)d_in[2];
    const float* tmax = (const float*)d_in[3];
    float* out = (float*)d_out;

    const int nblocks = BB * 8;  // 512: 2 per CU, LDS-capped
    sample_kernel<<<nblocks, 512, 0, stream>>>(X, eps, tmin, tmax, out);
}